// Round 2
// baseline (12615.276 us; speedup 1.0000x reference)
//
#include <hip/hip_runtime.h>
#include <math.h>

using floatx4 = __attribute__((ext_vector_type(4))) float;
using bf16x8  = __attribute__((ext_vector_type(8))) __bf16;
using ushort8 = __attribute__((ext_vector_type(8))) unsigned short;

// ---------- scalar helpers ----------
__device__ __forceinline__ float b2f(unsigned short u) {
  unsigned v = ((unsigned)u) << 16; float f; __builtin_memcpy(&f, &v, 4); return f;
}
__device__ __forceinline__ unsigned short f2b(float f) {
  unsigned u; __builtin_memcpy(&u, &f, 4);
  u += 0x7fffu + ((u >> 16) & 1u);          // RNE
  return (unsigned short)(u >> 16);
}
__device__ __forceinline__ float gelu_f(float x) {
  return 0.5f * x * (1.0f + erff(x * 0.7071067811865475f));
}
__device__ __forceinline__ float gelu_d(float x) {
  float cdf = 0.5f * (1.0f + erff(x * 0.7071067811865475f));
  float pdf = 0.3989422804014327f * expf(-0.5f * x * x);
  return cdf + x * pdf;
}
__device__ __forceinline__ float wred(float v) {
  #pragma unroll
  for (int off = 32; off > 0; off >>= 1) v += __shfl_xor(v, off, 64);
  return v;
}
__device__ __forceinline__ void gload16(const unsigned short* g, unsigned short* l) {
  __builtin_amdgcn_global_load_lds(
      (__attribute__((address_space(1))) void*)(g),
      (__attribute__((address_space(3))) void*)(l), 16, 0, 0);
}

// ---------- GEMM: C[M,N] = A[M,K] * Bt[N,K]^T ----------
// MODE 0: +bias all rows, bf16 out            (context GEMMs)
// MODE 1: +bias all rows, gelu, bf16 out      (Wc1)
// MODE 2: +bias even rows (+bias2), bf16 out  (input GEMM, Wvo, Wm2)
// MODE 3: +bias even rows, gelu-JVP pairs     (Wm1, Wp1)
// MODE 4: +bias even rows, f32 out            (Wp2)
template<int MODE>
__global__ __launch_bounds__(256) void gemm_bt_k(
    const unsigned short* __restrict__ A, const unsigned short* __restrict__ Bt,
    void* __restrict__ C, const float* __restrict__ bias,
    const float* __restrict__ bias2, int M, int N, int K)
{
  __shared__ unsigned short As[128 * 32];
  __shared__ unsigned short Bs[128 * 32];
  const int tid  = threadIdx.x;
  const int lane = tid & 63;
  const int wave = tid >> 6;
  const int row0 = blockIdx.y * 128;
  const int col0 = blockIdx.x * 128;

  const int sr = wave * 32 + (lane >> 2);
  const int sk = (lane & 3) * 8;
  const unsigned short* Ag0 = A  + (size_t)(row0 + sr) * K + sk;
  const unsigned short* Ag1 = Ag0 + (size_t)16 * K;
  const unsigned short* Bg0 = Bt + (size_t)(col0 + sr) * K + sk;
  const unsigned short* Bg1 = Bg0 + (size_t)16 * K;
  unsigned short* As0 = &As[wave * 1024];
  unsigned short* Bs0 = &Bs[wave * 1024];

  const int wr = wave >> 1, wc = wave & 1;
  const int mrow = lane & 15;
  const int kq = (lane >> 4) * 8;

  floatx4 acc[4][4];
  const floatx4 zf4 = {0.f, 0.f, 0.f, 0.f};
  #pragma unroll
  for (int i = 0; i < 4; i++)
    #pragma unroll
    for (int j = 0; j < 4; j++) acc[i][j] = zf4;

  for (int k0 = 0; k0 < K; k0 += 32) {
    __syncthreads();
    gload16(Ag0 + k0, As0);
    gload16(Ag1 + k0, As0 + 512);
    gload16(Bg0 + k0, Bs0);
    gload16(Bg1 + k0, Bs0 + 512);
    __syncthreads();
    bf16x8 af[4], bfr[4];
    #pragma unroll
    for (int t = 0; t < 4; t++)
      af[t] = *(const bf16x8*)&As[(wr * 64 + t * 16 + mrow) * 32 + kq];
    #pragma unroll
    for (int t = 0; t < 4; t++)
      bfr[t] = *(const bf16x8*)&Bs[(wc * 64 + t * 16 + mrow) * 32 + kq];
    #pragma unroll
    for (int i = 0; i < 4; i++)
      #pragma unroll
      for (int j = 0; j < 4; j++)
        acc[i][j] = __builtin_amdgcn_mfma_f32_16x16x32_bf16(af[i], bfr[j], acc[i][j], 0, 0, 0);
  }

  const int quad = lane >> 4;
  const int cl = lane & 15;
  #pragma unroll
  for (int j = 0; j < 4; j++) {
    int col = col0 + wc * 64 + j * 16 + cl;
    float bb = bias ? bias[col] : 0.f;
    if (MODE >= 2) { if (bias2) bb += bias2[col]; }
    #pragma unroll
    for (int i = 0; i < 4; i++) {
      int rbase = row0 + wr * 64 + i * 16 + quad * 4;   // rbase % 4 == 0
      if (MODE == 3) {
        #pragma unroll
        for (int pp = 0; pp < 2; pp++) {
          float p = acc[i][j][2 * pp] + bb;        // primal (even row)
          float t = acc[i][j][2 * pp + 1];         // tangent (odd row)
          ((unsigned short*)C)[(size_t)(rbase + 2 * pp) * N + col]     = f2b(gelu_f(p));
          ((unsigned short*)C)[(size_t)(rbase + 2 * pp + 1) * N + col] = f2b(gelu_d(p) * t);
        }
      } else {
        #pragma unroll
        for (int rr = 0; rr < 4; rr++) {
          int row = rbase + rr;
          float v = acc[i][j][rr];
          if (MODE == 0 || MODE == 1) v += bb;
          if (MODE == 2 || MODE == 4) { if ((row & 1) == 0) v += bb; }
          if (MODE == 1) v = gelu_f(v);
          if (MODE == 4) ((float*)C)[(size_t)row * N + col] = v;
          else           ((unsigned short*)C)[(size_t)row * N + col] = f2b(v);
        }
      }
    }
  }
}

// ---------- transpose+cast: W[K,N] f32 -> Wt[N,K] bf16 (batched over z) ----------
__global__ void transpose_cast_k(const float* __restrict__ W,
                                 unsigned short* __restrict__ Wt, int K, int N)
{
  __shared__ float tile[32][33];
  size_t off = (size_t)blockIdx.z * K * N;
  const float* Wp = W + off;
  unsigned short* Wtp = Wt + off;
  int bx = blockIdx.x, by = blockIdx.y;
  int tx = threadIdx.x, ty = threadIdx.y;
  #pragma unroll
  for (int i = ty; i < 32; i += 8)
    tile[i][tx] = Wp[(size_t)(by * 32 + i) * N + bx * 32 + tx];
  __syncthreads();
  #pragma unroll
  for (int i = ty; i < 32; i += 8)
    Wtp[(size_t)(bx * 32 + i) * K + by * 32 + tx] = f2b(tile[tx][i]);
}

// ---------- combined weight (f32 accumulate): Wt[l][out*H+in] = sum_k Wa[l][in,k]*Wb[l][k,out] ----------
__global__ __launch_bounds__(256) void combine_wt_k(
    const float* __restrict__ Wa, const float* __restrict__ Wb,
    unsigned short* __restrict__ Wt, int H)
{
  int in  = blockIdx.x * blockDim.x + threadIdx.x;
  int out = blockIdx.y;
  int l   = blockIdx.z;
  const float* A1 = Wa + (size_t)l * H * H;
  const float* A2 = Wb + (size_t)l * H * H;
  float s = 0.f;
  for (int k = 0; k < H; k++) s += A1[(size_t)in * H + k] * A2[(size_t)k * H + out];
  Wt[(size_t)l * H * H + (size_t)out * H + in] = f2b(s);
}

// ---------- combined bias: bout[l][out] = sum_k bv[l][k]*Wb[l][k,out] + bo[l][out] ----------
__global__ __launch_bounds__(256) void combine_bias_k(
    const float* __restrict__ bvp, const float* __restrict__ Wb,
    const float* __restrict__ bo, float* __restrict__ bout, int H)
{
  int out = blockIdx.x * blockDim.x + threadIdx.x;
  int l   = blockIdx.y;
  const float* A2 = Wb + (size_t)l * H * H;
  float s = bo[(size_t)l * H + out];
  for (int k = 0; k < H; k++) s += bvp[(size_t)l * H + k] * A2[(size_t)k * H + out];
  bout[(size_t)l * H + out] = s;
}

// ---------- LN-JVP; interleaved pair rows (2w, 2w+1), in-place on h ----------
__global__ __launch_bounds__(256) void ln_jvp_k(
    unsigned short* h, const unsigned short* __restrict__ r,
    const float* __restrict__ g, const float* __restrict__ be,
    const unsigned short* __restrict__ xatt, const float* __restrict__ sc_p,
    int Bhalf, int H)
{
  int gw = (int)((blockIdx.x * blockDim.x + threadIdx.x) >> 6);
  int lane = threadIdx.x & 63;
  if (gw >= Bhalf) return;
  int c0 = lane * 8;
  size_t op = (size_t)(2 * gw) * H + c0;
  size_t ot = op + H;
  ushort8 hp = *(const ushort8*)&h[op];
  ushort8 ht = *(const ushort8*)&h[ot];
  ushort8 rp = *(const ushort8*)&r[op];
  ushort8 rt = *(const ushort8*)&r[ot];
  float xv[8], dv[8];
  float s1 = 0.f, s2 = 0.f, sd = 0.f;
  #pragma unroll
  for (int j = 0; j < 8; j++) {
    xv[j] = b2f(hp[j]) + b2f(rp[j]);
    dv[j] = b2f(ht[j]) + b2f(rt[j]);
    s1 += xv[j]; s2 += xv[j] * xv[j]; sd += dv[j];
  }
  s1 = wred(s1); s2 = wred(s2); sd = wred(sd);
  float inv = 1.0f / (float)H;
  float m = s1 * inv;
  float var = s2 * inv - m * m;
  float rstd = rsqrtf(var + 1e-5f);
  float dm = sd * inv;
  float c = 0.f;
  #pragma unroll
  for (int j = 0; j < 8; j++) c += (xv[j] - m) * dv[j];
  c = wred(c);
  float cm = c * inv * rstd;  // mean(xhat * dx)
  float sl = sc_p ? *sc_p : 0.f;
  ushort8 oy, od;
  #pragma unroll
  for (int j = 0; j < 8; j++) {
    float xh = (xv[j] - m) * rstd;
    float gg = g[c0 + j];
    float y = xh * gg + be[c0 + j];
    if (xatt) y += sl * b2f(xatt[(size_t)gw * H + c0 + j]);
    float dy = gg * rstd * (dv[j] - dm - xh * cm);
    oy[j] = f2b(y); od[j] = f2b(dy);
  }
  *(ushort8*)&h[op] = oy;
  *(ushort8*)&h[ot] = od;
}

// ---------- f32 -> bf16 cast ----------
__global__ __launch_bounds__(256) void cast_k(const float* __restrict__ in,
                                              unsigned short* __restrict__ out, size_t n) {
  size_t i = blockIdx.x * blockDim.x + threadIdx.x;
  if (i < n) out[i] = f2b(in[i]);
}

// ---------- all S time embeddings: tvecs[s][H] ----------
__global__ __launch_bounds__(512) void temb_all_k(
    const float* __restrict__ Wt1, const float* __restrict__ bt1,
    const float* __restrict__ Wt2, const float* __restrict__ bt2,
    float dtv, float* __restrict__ tvecs, int H)
{
  __shared__ float e[512];
  int j = threadIdx.x;
  float t = fminf(fmaxf((float)blockIdx.x * dtv, 0.f), 1.f);
  e[j] = gelu_f(t * Wt1[j] + bt1[j]);
  __syncthreads();
  float s = bt2[j];
  for (int k = 0; k < H; k++) s += e[k] * Wt2[(size_t)k * H + j];
  tvecs[(size_t)blockIdx.x * H + j] = s;
}

// ---------- init: zf=x, ld=0, Abuf interleaved [z;u] ----------
__global__ __launch_bounds__(256) void init_k(
    const float* __restrict__ x, const float* __restrict__ u0,
    float* __restrict__ zf, float* __restrict__ ld,
    unsigned short* __restrict__ Abuf, int BF, int Bsz, int F)
{
  int i = (int)(blockIdx.x * blockDim.x + threadIdx.x);
  if (i < BF) {
    int r = i / F, c = i - r * F;
    float v = x[i];
    zf[i] = v;
    Abuf[(size_t)(2 * r) * F + c]     = f2b(v);
    Abuf[(size_t)(2 * r + 1) * F + c] = f2b(u0[i]);
  }
  if (i < Bsz) ld[i] = 0.f;
}

// ---------- Euler update + Hutchinson; interleaved vout rows ----------
__global__ __launch_bounds__(256) void update_k(
    const float* __restrict__ vout, const float* __restrict__ u_next,
    const float* __restrict__ u_cur, float* __restrict__ zf,
    float* __restrict__ ld, unsigned short* __restrict__ Abuf,
    int Bsz, int F, float dtv)
{
  int wid = (int)((blockIdx.x * blockDim.x + threadIdx.x) >> 6);
  int lane = threadIdx.x & 63;
  if (wid >= Bsz) return;
  int c = lane * 2;
  size_t zo = (size_t)wid * F + c;            // zf / u row
  size_t vp = (size_t)(2 * wid) * F + c;      // primal v row
  size_t vt = vp + F;                         // tangent (Ju) row
  float v0 = vout[vp], v1 = vout[vp + 1];
  float z0 = zf[zo] + v0 * dtv, z1 = zf[zo + 1] + v1 * dtv;
  zf[zo] = z0; zf[zo + 1] = z1;
  Abuf[vp] = f2b(z0); Abuf[vp + 1] = f2b(z1);
  float dot = u_cur[zo] * vout[vt] + u_cur[zo + 1] * vout[vt + 1];
  dot = wred(dot);
  if (lane == 0) ld[wid] += dot * dtv;
  if (u_next) { Abuf[vt] = f2b(u_next[zo]); Abuf[vt + 1] = f2b(u_next[zo + 1]); }
}

// ---------- write outputs ----------
__global__ __launch_bounds__(256) void final_k(
    const float* __restrict__ zf, const float* __restrict__ ld,
    float* __restrict__ out, int BF, int Bsz)
{
  int i = (int)(blockIdx.x * blockDim.x + threadIdx.x);
  if (i < BF) out[i] = zf[i];
  if (i < Bsz) out[BF + i] = ld[i];
}

extern "C" void kernel_launch(void* const* d_in, const int* in_sizes, int n_in,
                              void* d_out, int out_size, void* d_ws, size_t ws_size,
                              hipStream_t stream) {
  constexpr int B = 8192, F = 128, C = 256, H = 512, L = 4, S = 10;
  constexpr int B2 = 2 * B;
  constexpr int BF = B * F;
  const float dtv = 1.0f / S;

  const float* x    = (const float*)d_in[0];
  const float* ctxI = (const float*)d_in[1];
  const float* u    = (const float*)d_in[2];
  const float* Wi   = (const float*)d_in[3];
  const float* bi   = (const float*)d_in[4];
  const float* Wt1  = (const float*)d_in[5];
  const float* bt1  = (const float*)d_in[6];
  const float* Wt2  = (const float*)d_in[7];
  const float* bt2  = (const float*)d_in[8];
  const float* Wc1  = (const float*)d_in[9];
  const float* bc1  = (const float*)d_in[10];
  const float* Wc2  = (const float*)d_in[11];
  const float* bc2  = (const float*)d_in[12];
  const float* Wv   = (const float*)d_in[13];
  const float* bv   = (const float*)d_in[14];
  const float* Woa  = (const float*)d_in[15];
  const float* boa  = (const float*)d_in[16];
  const float* g1   = (const float*)d_in[17];
  const float* be1  = (const float*)d_in[18];
  const float* Wm1  = (const float*)d_in[19];
  const float* bm1  = (const float*)d_in[20];
  const float* Wm2  = (const float*)d_in[21];
  const float* bm2  = (const float*)d_in[22];
  const float* g2   = (const float*)d_in[23];
  const float* be2  = (const float*)d_in[24];
  const float* Wcv  = (const float*)d_in[25];
  const float* bcv  = (const float*)d_in[26];
  const float* Wco  = (const float*)d_in[27];
  const float* bco  = (const float*)d_in[28];
  const float* scal = (const float*)d_in[29];
  const float* Wp1  = (const float*)d_in[30];
  const float* bp1  = (const float*)d_in[31];
  const float* Wp2  = (const float*)d_in[32];
  const float* bp2  = (const float*)d_in[33];

  // ---- workspace layout ----
  char* wp = (char*)d_ws;
  auto alloc = [&](size_t bytes) -> void* {
    void* r = (void*)wp;
    wp += (bytes + 255) & ~(size_t)255;
    return r;
  };
  unsigned short* wWit  = (unsigned short*)alloc((size_t)H * F * 2);
  unsigned short* wWc1t = (unsigned short*)alloc((size_t)2 * H * C * 2);
  unsigned short* wWc2t = (unsigned short*)alloc((size_t)H * 2 * H * 2);
  unsigned short* wWvoT = (unsigned short*)alloc((size_t)L * H * H * 2);  // combined Wv@Woa, [out,in]
  unsigned short* wCtxT = (unsigned short*)alloc((size_t)L * H * H * 2);  // combined Wcv@Wco
  unsigned short* wWm1t = (unsigned short*)alloc((size_t)L * 4 * H * H * 2);
  unsigned short* wWm2t = (unsigned short*)alloc((size_t)L * H * 4 * H * 2);
  unsigned short* wWp1t = (unsigned short*)alloc((size_t)H * H * 2);
  unsigned short* wWp2t = (unsigned short*)alloc((size_t)F * H * 2);
  float* bvo            = (float*)alloc((size_t)L * H * 4);
  float* cbvo           = (float*)alloc((size_t)L * H * 4);
  float* tvecs          = (float*)alloc((size_t)S * H * 4);
  unsigned short* ctxc  = (unsigned short*)alloc((size_t)B * C * 2);
  unsigned short* Abuf  = (unsigned short*)alloc((size_t)B2 * F * 2);
  unsigned short* hbuf  = (unsigned short*)alloc((size_t)B2 * H * 2);
  unsigned short* tmp2  = (unsigned short*)alloc((size_t)B2 * H * 2);
  unsigned short* mbuf  = (unsigned short*)alloc((size_t)B2 * 4 * H * 2);
  unsigned short* xattb = (unsigned short*)alloc((size_t)L * B * H * 2);
  float* vout           = (float*)alloc((size_t)B2 * F * 4);
  float* zf             = (float*)alloc((size_t)B * F * 4);
  float* ldb            = (float*)alloc((size_t)B * 4);
  (void)ws_size; (void)in_sizes; (void)n_in; (void)out_size;

  auto T = [&](const float* W, unsigned short* Wt, int K, int N, int Lz) {
    dim3 g(N / 32, K / 32, Lz);
    transpose_cast_k<<<g, dim3(32, 8), 0, stream>>>(W, Wt, K, N);
  };
  auto G = [&](int mode, const unsigned short* A, const unsigned short* Bt, void* Cc,
               const float* bias, const float* bias2, int M, int N, int K) {
    dim3 g(N / 128, M / 128);
    switch (mode) {
      case 0: gemm_bt_k<0><<<g, 256, 0, stream>>>(A, Bt, Cc, bias, bias2, M, N, K); break;
      case 1: gemm_bt_k<1><<<g, 256, 0, stream>>>(A, Bt, Cc, bias, bias2, M, N, K); break;
      case 2: gemm_bt_k<2><<<g, 256, 0, stream>>>(A, Bt, Cc, bias, bias2, M, N, K); break;
      case 3: gemm_bt_k<3><<<g, 256, 0, stream>>>(A, Bt, Cc, bias, bias2, M, N, K); break;
      case 4: gemm_bt_k<4><<<g, 256, 0, stream>>>(A, Bt, Cc, bias, bias2, M, N, K); break;
    }
  };

  // ---- weight prep ----
  T(Wi,  wWit,  F, H, 1);
  T(Wc1, wWc1t, C, 2 * H, 1);
  T(Wc2, wWc2t, 2 * H, H, 1);
  T(Wm1, wWm1t, H, 4 * H, L);
  T(Wm2, wWm2t, 4 * H, H, L);
  T(Wp1, wWp1t, H, H, 1);
  T(Wp2, wWp2t, H, F, 1);
  // combined attn weights in f32 accumulate: Wvo^T[out,in] = sum_k Wv[in,k]*Woa[k,out]
  combine_wt_k<<<dim3(H / 256, H, L), 256, 0, stream>>>(Wv,  Woa, wWvoT, H);
  combine_wt_k<<<dim3(H / 256, H, L), 256, 0, stream>>>(Wcv, Wco, wCtxT, H);
  combine_bias_k<<<dim3(H / 256, L), 256, 0, stream>>>(bv,  Woa, boa, bvo,  H);
  combine_bias_k<<<dim3(H / 256, L), 256, 0, stream>>>(bcv, Wco, bco, cbvo, H);

  // ---- context path (z-independent): xatt[l] = ctx @ (Wcv@Wco) + (bcv@Wco+bco) ----
  cast_k<<<(B * C + 255) / 256, 256, 0, stream>>>(ctxI, ctxc, (size_t)B * C);
  G(1, ctxc, wWc1t, mbuf, bc1, nullptr, B, 2 * H, C);           // gelu fused
  G(0, mbuf, wWc2t, tmp2, bc2, nullptr, B, H, 2 * H);
  for (int l = 0; l < L; l++)
    G(0, tmp2, wCtxT + (size_t)l * H * H, xattb + (size_t)l * B * H,
      cbvo + l * H, nullptr, B, H, H);

  temb_all_k<<<S, H, 0, stream>>>(Wt1, bt1, Wt2, bt2, dtv, tvecs, H);
  init_k<<<(BF + 255) / 256, 256, 0, stream>>>(x, u, zf, ldb, Abuf, BF, B, F);

  // ---- S Euler steps; rows interleaved (2i primal, 2i+1 tangent) ----
  for (int s = 0; s < S; s++) {
    G(2, Abuf, wWit, hbuf, bi, tvecs + (size_t)s * H, B2, H, F);
    for (int l = 0; l < L; l++) {
      size_t o2 = (size_t)l * H * H;
      size_t om = (size_t)l * 4 * H * H;
      G(2, hbuf, wWvoT + o2, tmp2, bvo + l * H, nullptr, B2, H, H);   // fused attn
      ln_jvp_k<<<B / 4, 256, 0, stream>>>(hbuf, tmp2, g1 + l * H, be1 + l * H,
                                          nullptr, nullptr, B, H);
      G(3, hbuf, wWm1t + om, mbuf, bm1 + (size_t)l * 4 * H, nullptr, B2, 4 * H, H); // gelu-JVP fused
      G(2, mbuf, wWm2t + om, tmp2, bm2 + l * H, nullptr, B2, H, 4 * H);
      ln_jvp_k<<<B / 4, 256, 0, stream>>>(hbuf, tmp2, g2 + l * H, be2 + l * H,
                                          xattb + (size_t)l * B * H, scal + l, B, H);
    }
    G(3, hbuf, wWp1t, tmp2, bp1, nullptr, B2, H, H);                  // gelu-JVP fused
    G(4, tmp2, wWp2t, vout, bp2, nullptr, B2, F, H);
    const float* u_cur = u + (size_t)s * BF;
    const float* u_next = (s + 1 < S) ? u + (size_t)(s + 1) * BF : nullptr;
    update_k<<<B / 4, 256, 0, stream>>>(vout, u_next, u_cur, zf, ldb, Abuf, B, F, dtv);
  }

  final_k<<<(BF + 255) / 256, 256, 0, stream>>>(zf, ldb, (float*)d_out, BF, B);
}

// Round 3
// 9440.269 us; speedup vs baseline: 1.3363x; 1.3363x over previous
//
#include <hip/hip_runtime.h>
#include <math.h>

using floatx4 = __attribute__((ext_vector_type(4))) float;
using bf16x8  = __attribute__((ext_vector_type(8))) __bf16;
using ushort8 = __attribute__((ext_vector_type(8))) unsigned short;

// ---------- scalar helpers ----------
__device__ __forceinline__ float b2f(unsigned short u) {
  unsigned v = ((unsigned)u) << 16; float f; __builtin_memcpy(&f, &v, 4); return f;
}
__device__ __forceinline__ unsigned short f2b(float f) {
  unsigned u; __builtin_memcpy(&u, &f, 4);
  u += 0x7fffu + ((u >> 16) & 1u);          // RNE
  return (unsigned short)(u >> 16);
}
__device__ __forceinline__ float gelu_f(float x) {
  return 0.5f * x * (1.0f + erff(x * 0.7071067811865475f));
}
__device__ __forceinline__ float gelu_d(float x) {
  float cdf = 0.5f * (1.0f + erff(x * 0.7071067811865475f));
  float pdf = 0.3989422804014327f * expf(-0.5f * x * x);
  return cdf + x * pdf;
}
__device__ __forceinline__ float wred(float v) {
  #pragma unroll
  for (int off = 32; off > 0; off >>= 1) v += __shfl_xor(v, off, 64);
  return v;
}
__device__ __forceinline__ void gload16(const unsigned short* g, unsigned short* l) {
  __builtin_amdgcn_global_load_lds(
      (__attribute__((address_space(1))) void*)(g),
      (__attribute__((address_space(3))) void*)(l), 16, 0, 0);
}

// ---------- GEMM: C[M,N] = A[M,K] * Bt[N,K]^T ----------
// MODE 0: +bias all rows, bf16 out            (context GEMMs, weight-combine)
// MODE 1: +bias all rows, gelu, bf16 out      (Wc1)
// MODE 2: +bias even rows (+bias2), bf16 out  (input GEMM, Wvo, Wm2)
// MODE 3: +bias even rows, gelu-JVP pairs     (Wm1, Wp1)
// MODE 4: +bias even rows, f32 out            (Wp2)
template<int MODE>
__global__ __launch_bounds__(256) void gemm_bt_k(
    const unsigned short* __restrict__ A, const unsigned short* __restrict__ Bt,
    void* __restrict__ C, const float* __restrict__ bias,
    const float* __restrict__ bias2, int M, int N, int K)
{
  __shared__ unsigned short As[128 * 32];
  __shared__ unsigned short Bs[128 * 32];
  const int tid  = threadIdx.x;
  const int lane = tid & 63;
  const int wave = tid >> 6;
  const int row0 = blockIdx.y * 128;
  const int col0 = blockIdx.x * 128;

  const int sr = wave * 32 + (lane >> 2);
  const int sk = (lane & 3) * 8;
  const unsigned short* Ag0 = A  + (size_t)(row0 + sr) * K + sk;
  const unsigned short* Ag1 = Ag0 + (size_t)16 * K;
  const unsigned short* Bg0 = Bt + (size_t)(col0 + sr) * K + sk;
  const unsigned short* Bg1 = Bg0 + (size_t)16 * K;
  unsigned short* As0 = &As[wave * 1024];
  unsigned short* Bs0 = &Bs[wave * 1024];

  const int wr = wave >> 1, wc = wave & 1;
  const int mrow = lane & 15;
  const int kq = (lane >> 4) * 8;

  floatx4 acc[4][4];
  const floatx4 zf4 = {0.f, 0.f, 0.f, 0.f};
  #pragma unroll
  for (int i = 0; i < 4; i++)
    #pragma unroll
    for (int j = 0; j < 4; j++) acc[i][j] = zf4;

  for (int k0 = 0; k0 < K; k0 += 32) {
    __syncthreads();
    gload16(Ag0 + k0, As0);
    gload16(Ag1 + k0, As0 + 512);
    gload16(Bg0 + k0, Bs0);
    gload16(Bg1 + k0, Bs0 + 512);
    __syncthreads();
    bf16x8 af[4], bfr[4];
    #pragma unroll
    for (int t = 0; t < 4; t++)
      af[t] = *(const bf16x8*)&As[(wr * 64 + t * 16 + mrow) * 32 + kq];
    #pragma unroll
    for (int t = 0; t < 4; t++)
      bfr[t] = *(const bf16x8*)&Bs[(wc * 64 + t * 16 + mrow) * 32 + kq];
    #pragma unroll
    for (int i = 0; i < 4; i++)
      #pragma unroll
      for (int j = 0; j < 4; j++)
        acc[i][j] = __builtin_amdgcn_mfma_f32_16x16x32_bf16(af[i], bfr[j], acc[i][j], 0, 0, 0);
  }

  const int quad = lane >> 4;
  const int cl = lane & 15;
  #pragma unroll
  for (int j = 0; j < 4; j++) {
    int col = col0 + wc * 64 + j * 16 + cl;
    float bb = bias ? bias[col] : 0.f;
    if (MODE >= 2) { if (bias2) bb += bias2[col]; }
    #pragma unroll
    for (int i = 0; i < 4; i++) {
      int rbase = row0 + wr * 64 + i * 16 + quad * 4;   // rbase % 4 == 0
      if (MODE == 3) {
        #pragma unroll
        for (int pp = 0; pp < 2; pp++) {
          float p = acc[i][j][2 * pp] + bb;        // primal (even row)
          float t = acc[i][j][2 * pp + 1];         // tangent (odd row)
          ((unsigned short*)C)[(size_t)(rbase + 2 * pp) * N + col]     = f2b(gelu_f(p));
          ((unsigned short*)C)[(size_t)(rbase + 2 * pp + 1) * N + col] = f2b(gelu_d(p) * t);
        }
      } else {
        #pragma unroll
        for (int rr = 0; rr < 4; rr++) {
          int row = rbase + rr;
          float v = acc[i][j][rr];
          if (MODE == 0 || MODE == 1) v += bb;
          if (MODE == 2 || MODE == 4) { if ((row & 1) == 0) v += bb; }
          if (MODE == 1) v = gelu_f(v);
          if (MODE == 4) ((float*)C)[(size_t)row * N + col] = v;
          else           ((unsigned short*)C)[(size_t)row * N + col] = f2b(v);
        }
      }
    }
  }
}

// ---------- transpose+cast: W[K,N] f32 -> Wt[N,K] bf16 (batched over z) ----------
__global__ void transpose_cast_k(const float* __restrict__ W,
                                 unsigned short* __restrict__ Wt, int K, int N)
{
  __shared__ float tile[32][33];
  size_t off = (size_t)blockIdx.z * K * N;
  const float* Wp = W + off;
  unsigned short* Wtp = Wt + off;
  int bx = blockIdx.x, by = blockIdx.y;
  int tx = threadIdx.x, ty = threadIdx.y;
  #pragma unroll
  for (int i = ty; i < 32; i += 8)
    tile[i][tx] = Wp[(size_t)(by * 32 + i) * N + bx * 32 + tx];
  __syncthreads();
  #pragma unroll
  for (int i = ty; i < 32; i += 8)
    Wtp[(size_t)(bx * 32 + i) * K + by * 32 + tx] = f2b(tile[tx][i]);
}

// ---------- combined bias: bout[l][out] = sum_k bv[l][k]*Wb[l][k,out] + bo[l][out] ----------
__global__ __launch_bounds__(256) void combine_bias_k(
    const float* __restrict__ bvp, const float* __restrict__ Wb,
    const float* __restrict__ bo, float* __restrict__ bout, int H)
{
  int out = blockIdx.x * blockDim.x + threadIdx.x;
  int l   = blockIdx.y;
  const float* A2 = Wb + (size_t)l * H * H;
  float s = bo[(size_t)l * H + out];
  for (int k = 0; k < H; k++) s += bvp[(size_t)l * H + k] * A2[(size_t)k * H + out];
  bout[(size_t)l * H + out] = s;
}

// ---------- LN-JVP; interleaved pair rows (2w, 2w+1), in-place on h ----------
__global__ __launch_bounds__(256) void ln_jvp_k(
    unsigned short* h, const unsigned short* __restrict__ r,
    const float* __restrict__ g, const float* __restrict__ be,
    const unsigned short* __restrict__ xatt, const float* __restrict__ sc_p,
    int Bhalf, int H)
{
  int gw = (int)((blockIdx.x * blockDim.x + threadIdx.x) >> 6);
  int lane = threadIdx.x & 63;
  if (gw >= Bhalf) return;
  int c0 = lane * 8;
  size_t op = (size_t)(2 * gw) * H + c0;
  size_t ot = op + H;
  ushort8 hp = *(const ushort8*)&h[op];
  ushort8 ht = *(const ushort8*)&h[ot];
  ushort8 rp = *(const ushort8*)&r[op];
  ushort8 rt = *(const ushort8*)&r[ot];
  float xv[8], dv[8];
  float s1 = 0.f, s2 = 0.f, sd = 0.f;
  #pragma unroll
  for (int j = 0; j < 8; j++) {
    xv[j] = b2f(hp[j]) + b2f(rp[j]);
    dv[j] = b2f(ht[j]) + b2f(rt[j]);
    s1 += xv[j]; s2 += xv[j] * xv[j]; sd += dv[j];
  }
  s1 = wred(s1); s2 = wred(s2); sd = wred(sd);
  float inv = 1.0f / (float)H;
  float m = s1 * inv;
  float var = s2 * inv - m * m;
  float rstd = rsqrtf(var + 1e-5f);
  float dm = sd * inv;
  float c = 0.f;
  #pragma unroll
  for (int j = 0; j < 8; j++) c += (xv[j] - m) * dv[j];
  c = wred(c);
  float cm = c * inv * rstd;  // mean(xhat * dx)
  float sl = sc_p ? *sc_p : 0.f;
  ushort8 oy, od;
  #pragma unroll
  for (int j = 0; j < 8; j++) {
    float xh = (xv[j] - m) * rstd;
    float gg = g[c0 + j];
    float y = xh * gg + be[c0 + j];
    if (xatt) y += sl * b2f(xatt[(size_t)gw * H + c0 + j]);
    float dy = gg * rstd * (dv[j] - dm - xh * cm);
    oy[j] = f2b(y); od[j] = f2b(dy);
  }
  *(ushort8*)&h[op] = oy;
  *(ushort8*)&h[ot] = od;
}

// ---------- f32 -> bf16 cast ----------
__global__ __launch_bounds__(256) void cast_k(const float* __restrict__ in,
                                              unsigned short* __restrict__ out, size_t n) {
  size_t i = blockIdx.x * blockDim.x + threadIdx.x;
  if (i < n) out[i] = f2b(in[i]);
}

// ---------- all S time embeddings: tvecs[s][H] ----------
__global__ __launch_bounds__(512) void temb_all_k(
    const float* __restrict__ Wt1, const float* __restrict__ bt1,
    const float* __restrict__ Wt2, const float* __restrict__ bt2,
    float dtv, float* __restrict__ tvecs, int H)
{
  __shared__ float e[512];
  int j = threadIdx.x;
  float t = fminf(fmaxf((float)blockIdx.x * dtv, 0.f), 1.f);
  e[j] = gelu_f(t * Wt1[j] + bt1[j]);
  __syncthreads();
  float s = bt2[j];
  for (int k = 0; k < H; k++) s += e[k] * Wt2[(size_t)k * H + j];
  tvecs[(size_t)blockIdx.x * H + j] = s;
}

// ---------- init: zf=x, ld=0, Abuf interleaved [z;u] ----------
__global__ __launch_bounds__(256) void init_k(
    const float* __restrict__ x, const float* __restrict__ u0,
    float* __restrict__ zf, float* __restrict__ ld,
    unsigned short* __restrict__ Abuf, int BF, int Bsz, int F)
{
  int i = (int)(blockIdx.x * blockDim.x + threadIdx.x);
  if (i < BF) {
    int r = i / F, c = i - r * F;
    float v = x[i];
    zf[i] = v;
    Abuf[(size_t)(2 * r) * F + c]     = f2b(v);
    Abuf[(size_t)(2 * r + 1) * F + c] = f2b(u0[i]);
  }
  if (i < Bsz) ld[i] = 0.f;
}

// ---------- Euler update + Hutchinson; interleaved vout rows ----------
__global__ __launch_bounds__(256) void update_k(
    const float* __restrict__ vout, const float* __restrict__ u_next,
    const float* __restrict__ u_cur, float* __restrict__ zf,
    float* __restrict__ ld, unsigned short* __restrict__ Abuf,
    int Bsz, int F, float dtv)
{
  int wid = (int)((blockIdx.x * blockDim.x + threadIdx.x) >> 6);
  int lane = threadIdx.x & 63;
  if (wid >= Bsz) return;
  int c = lane * 2;
  size_t zo = (size_t)wid * F + c;            // zf / u row
  size_t vp = (size_t)(2 * wid) * F + c;      // primal v row
  size_t vt = vp + F;                         // tangent (Ju) row
  float v0 = vout[vp], v1 = vout[vp + 1];
  float z0 = zf[zo] + v0 * dtv, z1 = zf[zo + 1] + v1 * dtv;
  zf[zo] = z0; zf[zo + 1] = z1;
  Abuf[vp] = f2b(z0); Abuf[vp + 1] = f2b(z1);
  float dot = u_cur[zo] * vout[vt] + u_cur[zo + 1] * vout[vt + 1];
  dot = wred(dot);
  if (lane == 0) ld[wid] += dot * dtv;
  if (u_next) { Abuf[vt] = f2b(u_next[zo]); Abuf[vt + 1] = f2b(u_next[zo + 1]); }
}

// ---------- write outputs ----------
__global__ __launch_bounds__(256) void final_k(
    const float* __restrict__ zf, const float* __restrict__ ld,
    float* __restrict__ out, int BF, int Bsz)
{
  int i = (int)(blockIdx.x * blockDim.x + threadIdx.x);
  if (i < BF) out[i] = zf[i];
  if (i < Bsz) out[BF + i] = ld[i];
}

extern "C" void kernel_launch(void* const* d_in, const int* in_sizes, int n_in,
                              void* d_out, int out_size, void* d_ws, size_t ws_size,
                              hipStream_t stream) {
  constexpr int B = 8192, F = 128, C = 256, H = 512, L = 4, S = 10;
  constexpr int B2 = 2 * B;
  constexpr int BF = B * F;
  const float dtv = 1.0f / S;

  const float* x    = (const float*)d_in[0];
  const float* ctxI = (const float*)d_in[1];
  const float* u    = (const float*)d_in[2];
  const float* Wi   = (const float*)d_in[3];
  const float* bi   = (const float*)d_in[4];
  const float* Wt1  = (const float*)d_in[5];
  const float* bt1  = (const float*)d_in[6];
  const float* Wt2  = (const float*)d_in[7];
  const float* bt2  = (const float*)d_in[8];
  const float* Wc1  = (const float*)d_in[9];
  const float* bc1  = (const float*)d_in[10];
  const float* Wc2  = (const float*)d_in[11];
  const float* bc2  = (const float*)d_in[12];
  const float* Wv   = (const float*)d_in[13];
  const float* bv   = (const float*)d_in[14];
  const float* Woa  = (const float*)d_in[15];
  const float* boa  = (const float*)d_in[16];
  const float* g1   = (const float*)d_in[17];
  const float* be1  = (const float*)d_in[18];
  const float* Wm1  = (const float*)d_in[19];
  const float* bm1  = (const float*)d_in[20];
  const float* Wm2  = (const float*)d_in[21];
  const float* bm2  = (const float*)d_in[22];
  const float* g2   = (const float*)d_in[23];
  const float* be2  = (const float*)d_in[24];
  const float* Wcv  = (const float*)d_in[25];
  const float* bcv  = (const float*)d_in[26];
  const float* Wco  = (const float*)d_in[27];
  const float* bco  = (const float*)d_in[28];
  const float* scal = (const float*)d_in[29];
  const float* Wp1  = (const float*)d_in[30];
  const float* bp1  = (const float*)d_in[31];
  const float* Wp2  = (const float*)d_in[32];
  const float* bp2  = (const float*)d_in[33];

  // ---- workspace layout ----
  char* wp = (char*)d_ws;
  auto alloc = [&](size_t bytes) -> void* {
    void* r = (void*)wp;
    wp += (bytes + 255) & ~(size_t)255;
    return r;
  };
  unsigned short* wWit  = (unsigned short*)alloc((size_t)H * F * 2);
  unsigned short* wWc1t = (unsigned short*)alloc((size_t)2 * H * C * 2);
  unsigned short* wWc2t = (unsigned short*)alloc((size_t)H * 2 * H * 2);
  unsigned short* wWvoT = (unsigned short*)alloc((size_t)L * H * H * 2);  // combined Wv@Woa, [out,in]
  unsigned short* wCtxT = (unsigned short*)alloc((size_t)L * H * H * 2);  // combined Wcv@Wco
  unsigned short* wWm1t = (unsigned short*)alloc((size_t)L * 4 * H * H * 2);
  unsigned short* wWm2t = (unsigned short*)alloc((size_t)L * H * 4 * H * 2);
  unsigned short* wWp1t = (unsigned short*)alloc((size_t)H * H * 2);
  unsigned short* wWp2t = (unsigned short*)alloc((size_t)F * H * 2);
  unsigned short* wOaT  = (unsigned short*)alloc((size_t)L * H * H * 2);  // Woa^T bf16 (combine A)
  unsigned short* wCoT  = (unsigned short*)alloc((size_t)L * H * H * 2);  // Wco^T bf16
  unsigned short* wVb   = (unsigned short*)alloc((size_t)L * H * H * 2);  // Wv flat bf16 (combine Bt)
  unsigned short* wCvb  = (unsigned short*)alloc((size_t)L * H * H * 2);  // Wcv flat bf16
  float* bvo            = (float*)alloc((size_t)L * H * 4);
  float* cbvo           = (float*)alloc((size_t)L * H * 4);
  float* tvecs          = (float*)alloc((size_t)S * H * 4);
  unsigned short* ctxc  = (unsigned short*)alloc((size_t)B * C * 2);
  unsigned short* Abuf  = (unsigned short*)alloc((size_t)B2 * F * 2);
  unsigned short* hbuf  = (unsigned short*)alloc((size_t)B2 * H * 2);
  unsigned short* tmp2  = (unsigned short*)alloc((size_t)B2 * H * 2);
  unsigned short* mbuf  = (unsigned short*)alloc((size_t)B2 * 4 * H * 2);
  unsigned short* xattb = (unsigned short*)alloc((size_t)L * B * H * 2);
  float* vout           = (float*)alloc((size_t)B2 * F * 4);
  float* zf             = (float*)alloc((size_t)B * F * 4);
  float* ldb            = (float*)alloc((size_t)B * 4);
  (void)ws_size; (void)in_sizes; (void)n_in; (void)out_size;

  auto T = [&](const float* W, unsigned short* Wt, int K, int N, int Lz) {
    dim3 g(N / 32, K / 32, Lz);
    transpose_cast_k<<<g, dim3(32, 8), 0, stream>>>(W, Wt, K, N);
  };
  auto G = [&](int mode, const unsigned short* A, const unsigned short* Bt, void* Cc,
               const float* bias, const float* bias2, int M, int N, int K) {
    dim3 g(N / 128, M / 128);
    switch (mode) {
      case 0: gemm_bt_k<0><<<g, 256, 0, stream>>>(A, Bt, Cc, bias, bias2, M, N, K); break;
      case 1: gemm_bt_k<1><<<g, 256, 0, stream>>>(A, Bt, Cc, bias, bias2, M, N, K); break;
      case 2: gemm_bt_k<2><<<g, 256, 0, stream>>>(A, Bt, Cc, bias, bias2, M, N, K); break;
      case 3: gemm_bt_k<3><<<g, 256, 0, stream>>>(A, Bt, Cc, bias, bias2, M, N, K); break;
      case 4: gemm_bt_k<4><<<g, 256, 0, stream>>>(A, Bt, Cc, bias, bias2, M, N, K); break;
    }
  };

  // ---- weight prep ----
  T(Wi,  wWit,  F, H, 1);
  T(Wc1, wWc1t, C, 2 * H, 1);
  T(Wc2, wWc2t, 2 * H, H, 1);
  T(Wm1, wWm1t, H, 4 * H, L);
  T(Wm2, wWm2t, 4 * H, H, L);
  T(Wp1, wWp1t, H, H, 1);
  T(Wp2, wWp2t, H, F, 1);
  // combined attn weight via MFMA GEMM (round 2's f32 combine_wt_k was 1.7ms each,
  // 26 GB/s uncoalesced — the MFMA path is ~10us per layer):
  //   wWvoT[out,in] = sum_k Woa^T[out,k] * Wv[in,k]  (A=Woa^T bf16, Bt=Wv bf16)
  T(Woa, wOaT, H, H, L);
  T(Wco, wCoT, H, H, L);
  cast_k<<<((size_t)L * H * H + 255) / 256, 256, 0, stream>>>(Wv,  wVb,  (size_t)L * H * H);
  cast_k<<<((size_t)L * H * H + 255) / 256, 256, 0, stream>>>(Wcv, wCvb, (size_t)L * H * H);
  for (int l = 0; l < L; l++) {
    size_t o2 = (size_t)l * H * H;
    G(0, wOaT + o2, wVb  + o2, wWvoT + o2, nullptr, nullptr, H, H, H);
    G(0, wCoT + o2, wCvb + o2, wCtxT + o2, nullptr, nullptr, H, H, H);
  }
  combine_bias_k<<<dim3(H / 256, L), 256, 0, stream>>>(bv,  Woa, boa, bvo,  H);
  combine_bias_k<<<dim3(H / 256, L), 256, 0, stream>>>(bcv, Wco, bco, cbvo, H);

  // ---- context path (z-independent): xatt[l] = ctx @ (Wcv@Wco) + (bcv@Wco+bco) ----
  cast_k<<<(B * C + 255) / 256, 256, 0, stream>>>(ctxI, ctxc, (size_t)B * C);
  G(1, ctxc, wWc1t, mbuf, bc1, nullptr, B, 2 * H, C);           // gelu fused
  G(0, mbuf, wWc2t, tmp2, bc2, nullptr, B, H, 2 * H);
  for (int l = 0; l < L; l++)
    G(0, tmp2, wCtxT + (size_t)l * H * H, xattb + (size_t)l * B * H,
      cbvo + l * H, nullptr, B, H, H);

  temb_all_k<<<S, H, 0, stream>>>(Wt1, bt1, Wt2, bt2, dtv, tvecs, H);
  init_k<<<(BF + 255) / 256, 256, 0, stream>>>(x, u, zf, ldb, Abuf, BF, B, F);

  // ---- S Euler steps; rows interleaved (2i primal, 2i+1 tangent) ----
  for (int s = 0; s < S; s++) {
    G(2, Abuf, wWit, hbuf, bi, tvecs + (size_t)s * H, B2, H, F);
    for (int l = 0; l < L; l++) {
      size_t o2 = (size_t)l * H * H;
      size_t om = (size_t)l * 4 * H * H;
      G(2, hbuf, wWvoT + o2, tmp2, bvo + l * H, nullptr, B2, H, H);   // fused attn
      ln_jvp_k<<<B / 4, 256, 0, stream>>>(hbuf, tmp2, g1 + l * H, be1 + l * H,
                                          nullptr, nullptr, B, H);
      G(3, hbuf, wWm1t + om, mbuf, bm1 + (size_t)l * 4 * H, nullptr, B2, 4 * H, H); // gelu-JVP fused
      G(2, mbuf, wWm2t + om, tmp2, bm2 + l * H, nullptr, B2, H, 4 * H);
      ln_jvp_k<<<B / 4, 256, 0, stream>>>(hbuf, tmp2, g2 + l * H, be2 + l * H,
                                          xattb + (size_t)l * B * H, scal + l, B, H);
    }
    G(3, hbuf, wWp1t, tmp2, bp1, nullptr, B2, H, H);                  // gelu-JVP fused
    G(4, tmp2, wWp2t, vout, bp2, nullptr, B2, F, H);
    const float* u_cur = u + (size_t)s * BF;
    const float* u_next = (s + 1 < S) ? u + (size_t)(s + 1) * BF : nullptr;
    update_k<<<B / 4, 256, 0, stream>>>(vout, u_next, u_cur, zf, ldb, Abuf, B, F, dtv);
  }

  final_k<<<(BF + 255) / 256, 256, 0, stream>>>(zf, ldb, (float*)d_out, BF, B);
}